// Round 12
// baseline (213.422 us; speedup 1.0000x reference)
//
#include <hip/hip_runtime.h>
#include <hip/hip_bf16.h>
#include <math.h>

#define N_NODES 50000
#define N_EDGES 800000
#define DIMS 5
#define IN_C 32
#define OUT_C 32
#define FEAT 160            // DIMS*OUT_C
#define ATT_LD 65           // 2*OUT_C+1
#define NEG_SLOPE 0.2f
#define BSHIFT 7
#define BROWS 128                                   // rows per bucket
#define NBUCK ((N_NODES + BROWS - 1) / BROWS)       // 391
#define CAP 2560                                    // max edges/bucket (mean 2048, +11 sigma)
#define K1_EPB 4096
#define K1_BLOCKS ((N_EDGES + K1_EPB - 1) / K1_EPB) // 196

// ---- K1: per-block LDS histogram + per-edge local rank; fedge conversion ----
__global__ __launch_bounds__(1024) void hist_kernel(
        const int* __restrict__ ei, float* __restrict__ fedge,
        int* __restrict__ ghist, unsigned short* __restrict__ lofs) {
    __shared__ int hist[NBUCK];
    int blk = blockIdx.x, t = threadIdx.x;
    if (t < NBUCK) hist[t] = 0;
    __syncthreads();
#pragma unroll
    for (int u = 0; u < 4; ++u) {
        int e = blk * K1_EPB + u * 1024 + t;
        if (e < N_EDGES) {
            int r = ei[e];
            int c = ei[N_EDGES + e];
            __builtin_nontemporal_store((float)r, &fedge[e]);
            __builtin_nontemporal_store((float)c, &fedge[N_EDGES + e]);
            int b = r >> BSHIFT;
            int lo = atomicAdd(&hist[b], 1);
            lofs[e] = (unsigned short)lo;
        }
    }
    __syncthreads();
    if (t < NBUCK) ghist[blk * NBUCK + t] = hist[t];
}

// ---- K2a: column sums -> btot[b] ----
__global__ void colsum_kernel(const int* __restrict__ ghist, int* __restrict__ btot) {
    __shared__ int red[256];
    int b = blockIdx.x, t = threadIdx.x;
    int s = 0;
    for (int blk = t; blk < K1_BLOCKS; blk += 256) s += ghist[blk * NBUCK + b];
    red[t] = s;
    __syncthreads();
    for (int off = 128; off > 0; off >>= 1) {
        if (t < off) red[t] += red[t + off];
        __syncthreads();
    }
    if (t == 0) btot[b] = red[0];
}

// ---- K2b: exclusive scan of btot -> bbase ----
__global__ void bscan2_kernel(const int* __restrict__ btot, int* __restrict__ bbase) {
    __shared__ int buf[512];
    int t = threadIdx.x;
    int v = (t < NBUCK) ? btot[t] : 0;
    buf[t] = v;
    __syncthreads();
    for (int off = 1; off < 512; off <<= 1) {
        int add = (t >= off) ? buf[t - off] : 0;
        __syncthreads();
        buf[t] += add;
        __syncthreads();
    }
    if (t < NBUCK) bbase[t] = buf[t] - v;
}

// ---- K2c: per-bucket exclusive scan over blocks -> base2[blk][b] ----
__global__ void colscan_kernel(const int* __restrict__ ghist, const int* __restrict__ bbase,
                               int* __restrict__ base2) {
    __shared__ int buf[256];
    int b = blockIdx.x, t = threadIdx.x;
    int v = (t < K1_BLOCKS) ? ghist[t * NBUCK + b] : 0;
    buf[t] = v;
    __syncthreads();
    for (int off = 1; off < 256; off <<= 1) {
        int add = (t >= off) ? buf[t - off] : 0;
        __syncthreads();
        buf[t] += add;
        __syncthreads();
    }
    if (t < K1_BLOCKS) base2[t * NBUCK + b] = bbase[b] + buf[t] - v;
}

// ---- K3: place edges into bucket-sorted staged[] (8B) + fused es (bf16, edge order) ----
__global__ __launch_bounds__(1024) void place_es_kernel(
        const int* __restrict__ ei, const unsigned short* __restrict__ lofs,
        const int* __restrict__ base2,
        const float* __restrict__ edge_attr,
        const float* __restrict__ ai, const float* __restrict__ aj,
        const float* __restrict__ att,
        int2* __restrict__ staged, unsigned short* __restrict__ es2) {
    __shared__ int lbase[NBUCK];
    __shared__ float satte[DIMS];
    int blk = blockIdx.x, t = threadIdx.x;
    if (t < NBUCK) lbase[t] = base2[blk * NBUCK + t];
    if (t < DIMS) satte[t] = att[t * ATT_LD + 2 * OUT_C];
    __syncthreads();
#pragma unroll
    for (int u = 0; u < 4; ++u) {
        int e = blk * K1_EPB + u * 1024 + t;
        if (e < N_EDGES) {
            int r = ei[e];
            int c = ei[N_EDGES + e];
            int b = r >> BSHIFT;
            staged[lbase[b] + (int)lofs[e]] = make_int2(c, (e << BSHIFT) | (r & (BROWS - 1)));
            const float* air = ai + r * DIMS;
            const float* ajr = aj + c * DIMS;
            const float* ea  = edge_attr + (size_t)e * DIMS;
#pragma unroll
            for (int d = 0; d < DIMS; ++d) {
                float s = air[d] + ajr[d] + ea[d] * satte[d];
                s = (s > 0.f) ? s : NEG_SLOPE * s;
                __hip_bfloat16 h = __float2bfloat16(__expf(s));
                es2[(size_t)e * DIMS + d] = *(unsigned short*)&h;
            }
        }
    }
}

// ---- build: per-bucket CSR in LDS -> rowStart + csr ----
__global__ __launch_bounds__(256) void build_kernel(
        const int2* __restrict__ staged, const int* __restrict__ btot,
        const int* __restrict__ bbase,
        int2* __restrict__ csr, int* __restrict__ rowStart) {
    __shared__ int2 sst[CAP];
    __shared__ int rcount[BROWS];
    __shared__ int rexcl[BROWS];
    __shared__ int sbuf[BROWS];
    int b = blockIdx.x;
    int t = threadIdx.x;
    int cnt  = btot[b];
    int base = bbase[b];
    const int2* sg = staged + base;
    for (int i = t; i < cnt; i += 256) sst[i] = sg[i];
    if (t < BROWS) rcount[t] = 0;
    __syncthreads();
    for (int i = t; i < cnt; i += 256) atomicAdd(&rcount[sst[i].y & (BROWS - 1)], 1);
    __syncthreads();
    if (t < BROWS) sbuf[t] = rcount[t];
    __syncthreads();
    for (int off = 1; off < BROWS; off <<= 1) {
        int add = (t < BROWS && t >= off) ? sbuf[t - off] : 0;
        __syncthreads();
        if (t < BROWS) sbuf[t] += add;
        __syncthreads();
    }
    if (t < BROWS) {
        rexcl[t] = sbuf[t] - rcount[t];
        int idx = b * BROWS + t;
        if (idx <= N_NODES) rowStart[idx] = base + rexcl[t];
        rcount[t] = 0;                 // reuse as per-row cursor
    }
    __syncthreads();
    for (int i = t; i < cnt; i += 256) {
        int2 p = sst[i];
        int rl = p.y & (BROWS - 1);
        int lp = atomicAdd(&rcount[rl], 1);
        csr[base + rexcl[rl] + lp] = make_int2(p.x, p.y >> BSHIFT);
    }
}

// ---- fused h (bf16) + ai/aj. thread = (n, og) ----
__global__ __launch_bounds__(256) void hfused_kernel(
        const float* __restrict__ x, const float* __restrict__ W,
        const float* __restrict__ att,
        __hip_bfloat16* __restrict__ h2,
        float* __restrict__ ai, float* __restrict__ aj) {
    int idx = blockIdx.x * 256 + threadIdx.x;
    if (idx >= N_NODES * 8) return;
    int n = idx >> 3;
    int og = idx & 7;
    const float4* xr4 = (const float4*)(x + (size_t)n * FEAT);

    float acc[DIMS][4];
#pragma unroll
    for (int d = 0; d < DIMS; ++d)
#pragma unroll
        for (int q = 0; q < 4; ++q) acc[d][q] = 0.f;

#pragma unroll
    for (int ib = 0; ib < 8; ++ib) {
        float xs[20];
#pragma unroll
        for (int q = 0; q < 5; ++q) {
            float4 v = xr4[ib * 5 + q];
            xs[q * 4 + 0] = v.x; xs[q * 4 + 1] = v.y;
            xs[q * 4 + 2] = v.z; xs[q * 4 + 3] = v.w;
        }
#pragma unroll
        for (int ii = 0; ii < 4; ++ii) {
            int i = ib * 4 + ii;
#pragma unroll
            for (int d = 0; d < DIMS; ++d) {
                float xv = xs[ii * 5 + d];
                float4 wv = *(const float4*)(W + ((d * IN_C + i) * OUT_C) + og * 4);
                acc[d][0] += xv * wv.x; acc[d][1] += xv * wv.y;
                acc[d][2] += xv * wv.z; acc[d][3] += xv * wv.w;
            }
        }
    }

    __hip_bfloat16* hp = h2 + (size_t)n * FEAT + og * 4;
#pragma unroll
    for (int d = 0; d < DIMS; ++d) {
        union { __hip_bfloat16 h[4]; uint2 u; } pk;
        pk.h[0] = __float2bfloat16(acc[d][0]);
        pk.h[1] = __float2bfloat16(acc[d][1]);
        pk.h[2] = __float2bfloat16(acc[d][2]);
        pk.h[3] = __float2bfloat16(acc[d][3]);
        *(uint2*)(hp + d * OUT_C) = pk.u;
    }

    float pa[DIMS], pb[DIMS];
#pragma unroll
    for (int d = 0; d < DIMS; ++d) {
        const float* at = att + d * ATT_LD + og * 4;
        const float* bt = at + OUT_C;
        pa[d] = acc[d][0] * at[0] + acc[d][1] * at[1] + acc[d][2] * at[2] + acc[d][3] * at[3];
        pb[d] = acc[d][0] * bt[0] + acc[d][1] * bt[1] + acc[d][2] * bt[2] + acc[d][3] * bt[3];
    }
#pragma unroll
    for (int m = 1; m < 8; m <<= 1) {
#pragma unroll
        for (int d = 0; d < DIMS; ++d) {
            pa[d] += __shfl_xor(pa[d], m, 8);
            pb[d] += __shfl_xor(pb[d], m, 8);
        }
    }
    if (og == 0) {
#pragma unroll
        for (int d = 0; d < DIMS; ++d) {
            ai[n * DIMS + d] = pa[d];
            aj[n * DIMS + d] = pb[d];
        }
    }
}

__device__ inline float bf2f(unsigned short u) {
    return __uint_as_float(((unsigned)u) << 16);
}

// ---- out: 320-thr blocks = 4 nodes x 2 groups x 40 lanes; LDS cross-group combine ----
__global__ __launch_bounds__(320) void out_kernel(
        const __hip_bfloat16* __restrict__ h2,
        const unsigned short* __restrict__ es2,
        const int2* __restrict__ csr,
        const int* __restrict__ rowStart,
        float* __restrict__ out, float* __restrict__ ssum) {
    __shared__ float sacc[4][40][4];
    __shared__ float sss[4][40];
    int tid  = threadIdx.x;
    int slot = tid / 80;               // node slot 0..3
    int rem  = tid - slot * 80;
    int grp  = rem / 40;               // 0 or 1
    int l    = rem - grp * 40;         // 0..39
    int node = blockIdx.x * 4 + slot;
    int d = l >> 3;                    // 8 lanes per d
    int start = rowStart[node];
    int end   = rowStart[node + 1];
    float a0 = 0.f, a1 = 0.f, a2 = 0.f, a3 = 0.f, ss = 0.f;
    int k = start + grp;
    for (; k + 14 < end; k += 16) {    // 8 edges per group per batch (stride 2)
        int cc[8], ee[8]; float av[8]; uint2 hv[8];
#pragma unroll
        for (int u = 0; u < 8; ++u) {
            int2 ce = csr[k + 2 * u];
            cc[u] = ce.x; ee[u] = ce.y;
        }
#pragma unroll
        for (int u = 0; u < 8; ++u) av[u] = bf2f(es2[(size_t)ee[u] * DIMS + d]);
#pragma unroll
        for (int u = 0; u < 8; ++u)
            hv[u] = *(const uint2*)(h2 + (size_t)cc[u] * FEAT + l * 4);
#pragma unroll
        for (int u = 0; u < 8; ++u) {
            float a = av[u];
            ss += a;
            a0 += a * __uint_as_float(hv[u].x << 16);
            a1 += a * __uint_as_float(hv[u].x & 0xffff0000u);
            a2 += a * __uint_as_float(hv[u].y << 16);
            a3 += a * __uint_as_float(hv[u].y & 0xffff0000u);
        }
    }
    for (; k < end; k += 2) {
        int2 ce = csr[k];
        float a = bf2f(es2[(size_t)ce.y * DIMS + d]);
        uint2 hv = *(const uint2*)(h2 + (size_t)ce.x * FEAT + l * 4);
        ss += a;
        a0 += a * __uint_as_float(hv.x << 16);
        a1 += a * __uint_as_float(hv.x & 0xffff0000u);
        a2 += a * __uint_as_float(hv.y << 16);
        a3 += a * __uint_as_float(hv.y & 0xffff0000u);
    }
    if (grp) {
        sacc[slot][l][0] = a0; sacc[slot][l][1] = a1;
        sacc[slot][l][2] = a2; sacc[slot][l][3] = a3;
        sss[slot][l] = ss;
    }
    __syncthreads();
    if (!grp) {
        a0 += sacc[slot][l][0]; a1 += sacc[slot][l][1];
        a2 += sacc[slot][l][2]; a3 += sacc[slot][l][3];
        ss += sss[slot][l];
        float inv = 1.f / (ss + 1e-16f);
        union { float f[4]; unsigned long long u[2]; } o;
        o.f[0] = a0 * inv; o.f[1] = a1 * inv; o.f[2] = a2 * inv; o.f[3] = a3 * inv;
        unsigned long long* op = (unsigned long long*)(out + (size_t)node * FEAT + l * 4);
        __builtin_nontemporal_store(o.u[0], op);
        __builtin_nontemporal_store(o.u[1], op + 1);
        if ((l & 7) == 0) ssum[node * DIMS + d] = ss;
    }
}

// ---- alpha = bf16(es) / ssum[row] ----
__global__ void alpha_kernel(const int* __restrict__ ei,
                             const unsigned short* __restrict__ es2,
                             const float* __restrict__ ssum,
                             float* __restrict__ alpha_buf) {
    int idx = blockIdx.x * blockDim.x + threadIdx.x;
    if (idx >= N_EDGES * DIMS) return;
    int e = idx / DIMS;
    int d = idx - e * DIMS;
    int r = ei[e];
    float a = bf2f(es2[idx]) / (ssum[r * DIMS + d] + 1e-16f);
    __builtin_nontemporal_store(a, &alpha_buf[idx]);
}

extern "C" void kernel_launch(void* const* d_in, const int* in_sizes, int n_in,
                              void* d_out, int out_size, void* d_ws, size_t ws_size,
                              hipStream_t stream) {
    const float* x         = (const float*)d_in[0];
    const int*   ei        = (const int*)d_in[1];
    const float* edge_attr = (const float*)d_in[2];
    const float* W         = (const float*)d_in[3];
    const float* att       = (const float*)d_in[4];

    float* out_buf   = (float*)d_out;                       // 8,000,000 f32
    float* alpha_buf = out_buf + (size_t)N_NODES * FEAT;    // 4,000,000 f32 (scratch until alpha)
    float* fedge     = alpha_buf + (size_t)N_EDGES * DIMS;  // 1,600,000 f32

    // scratch inside the alpha output region (dead until alpha_kernel runs last):
    int2* staged = (int2*)alpha_buf;                        // 6,400,000 B
    unsigned short* lofs = (unsigned short*)((char*)alpha_buf + 6400000); // 1,600,000 B

    char* wsb = (char*)d_ws;
    __hip_bfloat16* h2 = (__hip_bfloat16*)wsb;              //  0 .. 16,000,000
    float* ai     = (float*)(wsb + 16000000);               // 1,000,000 B
    float* aj     = (float*)(wsb + 17000000);               // 1,000,000 B
    float* ssum   = (float*)(wsb + 18000000);               // 1,000,000 B
    int2* csr     = (int2*)(wsb + 19000000);                // 6,400,000 B
    int* ghist    = (int*)(wsb + 25400000);                 // 306,544 B
    int* base2    = (int*)(wsb + 25710000);                 // 306,544 B
    int* btot     = (int*)(wsb + 26020000);                 // 1,564 B
    int* bbase    = (int*)(wsb + 26022000);                 // 1,564 B
    int* rowStart = (int*)(wsb + 26024000);                 // 200,004 B
    unsigned short* es2 = (unsigned short*)(wsb + 26225000);// 8,000,000 B -> end ~34.2 MB

    const int B = 256;

    hist_kernel<<<K1_BLOCKS, 1024, 0, stream>>>(ei, fedge, ghist, lofs);
    hfused_kernel<<<(N_NODES * 8 + B - 1) / B, B, 0, stream>>>(x, W, att, h2, ai, aj);
    colsum_kernel<<<NBUCK, 256, 0, stream>>>(ghist, btot);
    bscan2_kernel<<<1, 512, 0, stream>>>(btot, bbase);
    colscan_kernel<<<NBUCK, 256, 0, stream>>>(ghist, bbase, base2);
    place_es_kernel<<<K1_BLOCKS, 1024, 0, stream>>>(ei, lofs, base2, edge_attr,
                                                    ai, aj, att, staged, es2);
    build_kernel<<<NBUCK, 256, 0, stream>>>(staged, btot, bbase, csr, rowStart);
    out_kernel<<<N_NODES / 4, 320, 0, stream>>>(h2, es2, csr, rowStart, out_buf, ssum);
    alpha_kernel<<<(N_EDGES * DIMS + B - 1) / B, B, 0, stream>>>(ei, es2, ssum, alpha_buf);
}

// Round 13
// 171.895 us; speedup vs baseline: 1.2416x; 1.2416x over previous
//
#include <hip/hip_runtime.h>
#include <hip/hip_bf16.h>
#include <math.h>

#define N_NODES 50000
#define N_EDGES 800000
#define DIMS 5
#define IN_C 32
#define OUT_C 32
#define FEAT 160            // DIMS*OUT_C
#define ATT_LD 65           // 2*OUT_C+1
#define NEG_SLOPE 0.2f
#define BSHIFT 7
#define BROWS 128                                   // rows per bucket
#define NBUCK ((N_NODES + BROWS - 1) / BROWS)       // 391
#define CAP 2560                                    // max edges/bucket (mean 2048, +11 sigma)
#define K1_EPB 4096
#define K1_BLOCKS ((N_EDGES + K1_EPB - 1) / K1_EPB) // 196

// ---- K1: per-block LDS histogram + per-edge local rank; fedge conversion ----
__global__ __launch_bounds__(1024) void hist_kernel(
        const int* __restrict__ ei, float* __restrict__ fedge,
        int* __restrict__ ghist, unsigned short* __restrict__ lofs) {
    __shared__ int hist[NBUCK];
    int blk = blockIdx.x, t = threadIdx.x;
    if (t < NBUCK) hist[t] = 0;
    __syncthreads();
#pragma unroll
    for (int u = 0; u < 4; ++u) {
        int e = blk * K1_EPB + u * 1024 + t;
        if (e < N_EDGES) {
            int r = ei[e];
            int c = ei[N_EDGES + e];
            __builtin_nontemporal_store((float)r, &fedge[e]);
            __builtin_nontemporal_store((float)c, &fedge[N_EDGES + e]);
            int b = r >> BSHIFT;
            int lo = atomicAdd(&hist[b], 1);
            lofs[e] = (unsigned short)lo;
        }
    }
    __syncthreads();
    if (t < NBUCK) ghist[blk * NBUCK + t] = hist[t];
}

// ---- K2a: column sums -> btot[b] ----
__global__ void colsum_kernel(const int* __restrict__ ghist, int* __restrict__ btot) {
    __shared__ int red[256];
    int b = blockIdx.x, t = threadIdx.x;
    int s = 0;
    for (int blk = t; blk < K1_BLOCKS; blk += 256) s += ghist[blk * NBUCK + b];
    red[t] = s;
    __syncthreads();
    for (int off = 128; off > 0; off >>= 1) {
        if (t < off) red[t] += red[t + off];
        __syncthreads();
    }
    if (t == 0) btot[b] = red[0];
}

// ---- K2b: exclusive scan of btot -> bbase ----
__global__ void bscan2_kernel(const int* __restrict__ btot, int* __restrict__ bbase) {
    __shared__ int buf[512];
    int t = threadIdx.x;
    int v = (t < NBUCK) ? btot[t] : 0;
    buf[t] = v;
    __syncthreads();
    for (int off = 1; off < 512; off <<= 1) {
        int add = (t >= off) ? buf[t - off] : 0;
        __syncthreads();
        buf[t] += add;
        __syncthreads();
    }
    if (t < NBUCK) bbase[t] = buf[t] - v;
}

// ---- K2c: per-bucket exclusive scan over blocks -> base2[blk][b] ----
__global__ void colscan_kernel(const int* __restrict__ ghist, const int* __restrict__ bbase,
                               int* __restrict__ base2) {
    __shared__ int buf[256];
    int b = blockIdx.x, t = threadIdx.x;
    int v = (t < K1_BLOCKS) ? ghist[t * NBUCK + b] : 0;
    buf[t] = v;
    __syncthreads();
    for (int off = 1; off < 256; off <<= 1) {
        int add = (t >= off) ? buf[t - off] : 0;
        __syncthreads();
        buf[t] += add;
        __syncthreads();
    }
    if (t < K1_BLOCKS) base2[t * NBUCK + b] = bbase[b] + buf[t] - v;
}

// ---- K3: place edges into bucket-sorted staged[] (8B) + fused es (bf16, edge order) ----
__global__ __launch_bounds__(1024) void place_es_kernel(
        const int* __restrict__ ei, const unsigned short* __restrict__ lofs,
        const int* __restrict__ base2,
        const float* __restrict__ edge_attr,
        const float* __restrict__ ai, const float* __restrict__ aj,
        const float* __restrict__ att,
        int2* __restrict__ staged, unsigned short* __restrict__ es2) {
    __shared__ int lbase[NBUCK];
    __shared__ float satte[DIMS];
    int blk = blockIdx.x, t = threadIdx.x;
    if (t < NBUCK) lbase[t] = base2[blk * NBUCK + t];
    if (t < DIMS) satte[t] = att[t * ATT_LD + 2 * OUT_C];
    __syncthreads();
#pragma unroll
    for (int u = 0; u < 4; ++u) {
        int e = blk * K1_EPB + u * 1024 + t;
        if (e < N_EDGES) {
            int r = ei[e];
            int c = ei[N_EDGES + e];
            int b = r >> BSHIFT;
            staged[lbase[b] + (int)lofs[e]] = make_int2(c, (e << BSHIFT) | (r & (BROWS - 1)));
            const float* air = ai + r * DIMS;
            const float* ajr = aj + c * DIMS;
            const float* ea  = edge_attr + (size_t)e * DIMS;
#pragma unroll
            for (int d = 0; d < DIMS; ++d) {
                float s = air[d] + ajr[d] + ea[d] * satte[d];
                s = (s > 0.f) ? s : NEG_SLOPE * s;
                __hip_bfloat16 h = __float2bfloat16(__expf(s));
                es2[(size_t)e * DIMS + d] = *(unsigned short*)&h;
            }
        }
    }
}

// ---- build: per-bucket CSR in LDS -> rowStart + csr ----
__global__ __launch_bounds__(256) void build_kernel(
        const int2* __restrict__ staged, const int* __restrict__ btot,
        const int* __restrict__ bbase,
        int2* __restrict__ csr, int* __restrict__ rowStart) {
    __shared__ int2 sst[CAP];
    __shared__ int rcount[BROWS];
    __shared__ int rexcl[BROWS];
    __shared__ int sbuf[BROWS];
    int b = blockIdx.x;
    int t = threadIdx.x;
    int cnt  = btot[b];
    int base = bbase[b];
    const int2* sg = staged + base;
    for (int i = t; i < cnt; i += 256) sst[i] = sg[i];
    if (t < BROWS) rcount[t] = 0;
    __syncthreads();
    for (int i = t; i < cnt; i += 256) atomicAdd(&rcount[sst[i].y & (BROWS - 1)], 1);
    __syncthreads();
    if (t < BROWS) sbuf[t] = rcount[t];
    __syncthreads();
    for (int off = 1; off < BROWS; off <<= 1) {
        int add = (t < BROWS && t >= off) ? sbuf[t - off] : 0;
        __syncthreads();
        if (t < BROWS) sbuf[t] += add;
        __syncthreads();
    }
    if (t < BROWS) {
        rexcl[t] = sbuf[t] - rcount[t];
        int idx = b * BROWS + t;
        if (idx <= N_NODES) rowStart[idx] = base + rexcl[t];
        rcount[t] = 0;                 // reuse as per-row cursor
    }
    __syncthreads();
    for (int i = t; i < cnt; i += 256) {
        int2 p = sst[i];
        int rl = p.y & (BROWS - 1);
        int lp = atomicAdd(&rcount[rl], 1);
        csr[base + rexcl[rl] + lp] = make_int2(p.x, p.y >> BSHIFT);
    }
}

// ---- fused h (bf16) + ai/aj. thread = (n, og) ----
__global__ __launch_bounds__(256) void hfused_kernel(
        const float* __restrict__ x, const float* __restrict__ W,
        const float* __restrict__ att,
        __hip_bfloat16* __restrict__ h2,
        float* __restrict__ ai, float* __restrict__ aj) {
    int idx = blockIdx.x * 256 + threadIdx.x;
    if (idx >= N_NODES * 8) return;
    int n = idx >> 3;
    int og = idx & 7;
    const float4* xr4 = (const float4*)(x + (size_t)n * FEAT);

    float acc[DIMS][4];
#pragma unroll
    for (int d = 0; d < DIMS; ++d)
#pragma unroll
        for (int q = 0; q < 4; ++q) acc[d][q] = 0.f;

#pragma unroll
    for (int ib = 0; ib < 8; ++ib) {
        float xs[20];
#pragma unroll
        for (int q = 0; q < 5; ++q) {
            float4 v = xr4[ib * 5 + q];
            xs[q * 4 + 0] = v.x; xs[q * 4 + 1] = v.y;
            xs[q * 4 + 2] = v.z; xs[q * 4 + 3] = v.w;
        }
#pragma unroll
        for (int ii = 0; ii < 4; ++ii) {
            int i = ib * 4 + ii;
#pragma unroll
            for (int d = 0; d < DIMS; ++d) {
                float xv = xs[ii * 5 + d];
                float4 wv = *(const float4*)(W + ((d * IN_C + i) * OUT_C) + og * 4);
                acc[d][0] += xv * wv.x; acc[d][1] += xv * wv.y;
                acc[d][2] += xv * wv.z; acc[d][3] += xv * wv.w;
            }
        }
    }

    __hip_bfloat16* hp = h2 + (size_t)n * FEAT + og * 4;
#pragma unroll
    for (int d = 0; d < DIMS; ++d) {
        union { __hip_bfloat16 h[4]; uint2 u; } pk;
        pk.h[0] = __float2bfloat16(acc[d][0]);
        pk.h[1] = __float2bfloat16(acc[d][1]);
        pk.h[2] = __float2bfloat16(acc[d][2]);
        pk.h[3] = __float2bfloat16(acc[d][3]);
        *(uint2*)(hp + d * OUT_C) = pk.u;
    }

    float pa[DIMS], pb[DIMS];
#pragma unroll
    for (int d = 0; d < DIMS; ++d) {
        const float* at = att + d * ATT_LD + og * 4;
        const float* bt = at + OUT_C;
        pa[d] = acc[d][0] * at[0] + acc[d][1] * at[1] + acc[d][2] * at[2] + acc[d][3] * at[3];
        pb[d] = acc[d][0] * bt[0] + acc[d][1] * bt[1] + acc[d][2] * bt[2] + acc[d][3] * bt[3];
    }
#pragma unroll
    for (int m = 1; m < 8; m <<= 1) {
#pragma unroll
        for (int d = 0; d < DIMS; ++d) {
            pa[d] += __shfl_xor(pa[d], m, 8);
            pb[d] += __shfl_xor(pb[d], m, 8);
        }
    }
    if (og == 0) {
#pragma unroll
        for (int d = 0; d < DIMS; ++d) {
            ai[n * DIMS + d] = pa[d];
            aj[n * DIMS + d] = pb[d];
        }
    }
}

__device__ inline float bf2f(unsigned short u) {
    return __uint_as_float(((unsigned)u) << 16);
}

// ---- out: 320-thr blocks, 8 nodes/block, 40 lanes/node; csr software prefetch ----
__global__ __launch_bounds__(320) void out_kernel(
        const __hip_bfloat16* __restrict__ h2,
        const unsigned short* __restrict__ es2,
        const int2* __restrict__ csr,
        const int* __restrict__ rowStart,
        float* __restrict__ out, float* __restrict__ ssum) {
    int g = threadIdx.x / 40;          // node group 0..7
    int l = threadIdx.x - g * 40;      // 0..39
    int node = blockIdx.x * 8 + g;
    int d = l >> 3;                    // 8 lanes per d
    int start = rowStart[node];
    int end   = rowStart[node + 1];
    float a0 = 0.f, a1 = 0.f, a2 = 0.f, a3 = 0.f, ss = 0.f;
    int k = start;
    if (end - k >= 8) {
        int2 ceA[8];
#pragma unroll
        for (int u = 0; u < 8; ++u) ceA[u] = csr[k + u];
        while (true) {
            int kn = k + 8;
            bool more = (end - kn >= 8);
            float av[8]; uint2 hv[8]; int2 ceB[8];
            // gathers for current batch (ceA already resident)
#pragma unroll
            for (int u = 0; u < 8; ++u) av[u] = bf2f(es2[(size_t)ceA[u].y * DIMS + d]);
#pragma unroll
            for (int u = 0; u < 8; ++u)
                hv[u] = *(const uint2*)(h2 + (size_t)ceA[u].x * FEAT + l * 4);
            // prefetch next batch's csr while gathers are in flight
            if (more) {
#pragma unroll
                for (int u = 0; u < 8; ++u) ceB[u] = csr[kn + u];
            }
#pragma unroll
            for (int u = 0; u < 8; ++u) {
                float a = av[u];
                ss += a;
                a0 += a * __uint_as_float(hv[u].x << 16);
                a1 += a * __uint_as_float(hv[u].x & 0xffff0000u);
                a2 += a * __uint_as_float(hv[u].y << 16);
                a3 += a * __uint_as_float(hv[u].y & 0xffff0000u);
            }
            k = kn;
            if (!more) break;
#pragma unroll
            for (int u = 0; u < 8; ++u) ceA[u] = ceB[u];
        }
    }
    for (; k < end; ++k) {
        int2 ce = csr[k];
        float a = bf2f(es2[(size_t)ce.y * DIMS + d]);
        uint2 hv = *(const uint2*)(h2 + (size_t)ce.x * FEAT + l * 4);
        ss += a;
        a0 += a * __uint_as_float(hv.x << 16);
        a1 += a * __uint_as_float(hv.x & 0xffff0000u);
        a2 += a * __uint_as_float(hv.y << 16);
        a3 += a * __uint_as_float(hv.y & 0xffff0000u);
    }
    float inv = 1.f / (ss + 1e-16f);
    union { float f[4]; unsigned long long u[2]; } o;
    o.f[0] = a0 * inv; o.f[1] = a1 * inv; o.f[2] = a2 * inv; o.f[3] = a3 * inv;
    unsigned long long* op = (unsigned long long*)(out + (size_t)node * FEAT + l * 4);
    __builtin_nontemporal_store(o.u[0], op);
    __builtin_nontemporal_store(o.u[1], op + 1);
    if ((l & 7) == 0) ssum[node * DIMS + d] = ss;
}

// ---- alpha = bf16(es) / ssum[row] ----
__global__ void alpha_kernel(const int* __restrict__ ei,
                             const unsigned short* __restrict__ es2,
                             const float* __restrict__ ssum,
                             float* __restrict__ alpha_buf) {
    int idx = blockIdx.x * blockDim.x + threadIdx.x;
    if (idx >= N_EDGES * DIMS) return;
    int e = idx / DIMS;
    int d = idx - e * DIMS;
    int r = ei[e];
    float a = bf2f(es2[idx]) / (ssum[r * DIMS + d] + 1e-16f);
    __builtin_nontemporal_store(a, &alpha_buf[idx]);
}

extern "C" void kernel_launch(void* const* d_in, const int* in_sizes, int n_in,
                              void* d_out, int out_size, void* d_ws, size_t ws_size,
                              hipStream_t stream) {
    const float* x         = (const float*)d_in[0];
    const int*   ei        = (const int*)d_in[1];
    const float* edge_attr = (const float*)d_in[2];
    const float* W         = (const float*)d_in[3];
    const float* att       = (const float*)d_in[4];

    float* out_buf   = (float*)d_out;                       // 8,000,000 f32
    float* alpha_buf = out_buf + (size_t)N_NODES * FEAT;    // 4,000,000 f32 (scratch until alpha)
    float* fedge     = alpha_buf + (size_t)N_EDGES * DIMS;  // 1,600,000 f32

    // scratch inside the alpha output region (dead until alpha_kernel runs last):
    int2* staged = (int2*)alpha_buf;                        // 6,400,000 B
    unsigned short* lofs = (unsigned short*)((char*)alpha_buf + 6400000); // 1,600,000 B

    char* wsb = (char*)d_ws;
    __hip_bfloat16* h2 = (__hip_bfloat16*)wsb;              //  0 .. 16,000,000
    float* ai     = (float*)(wsb + 16000000);               // 1,000,000 B
    float* aj     = (float*)(wsb + 17000000);               // 1,000,000 B
    float* ssum   = (float*)(wsb + 18000000);               // 1,000,000 B
    int2* csr     = (int2*)(wsb + 19000000);                // 6,400,000 B
    int* ghist    = (int*)(wsb + 25400000);                 // 306,544 B
    int* base2    = (int*)(wsb + 25710000);                 // 306,544 B
    int* btot     = (int*)(wsb + 26020000);                 // 1,564 B
    int* bbase    = (int*)(wsb + 26022000);                 // 1,564 B
    int* rowStart = (int*)(wsb + 26024000);                 // 200,004 B
    unsigned short* es2 = (unsigned short*)(wsb + 26225000);// 8,000,000 B -> end ~34.2 MB

    const int B = 256;

    hist_kernel<<<K1_BLOCKS, 1024, 0, stream>>>(ei, fedge, ghist, lofs);
    hfused_kernel<<<(N_NODES * 8 + B - 1) / B, B, 0, stream>>>(x, W, att, h2, ai, aj);
    colsum_kernel<<<NBUCK, 256, 0, stream>>>(ghist, btot);
    bscan2_kernel<<<1, 512, 0, stream>>>(btot, bbase);
    colscan_kernel<<<NBUCK, 256, 0, stream>>>(ghist, bbase, base2);
    place_es_kernel<<<K1_BLOCKS, 1024, 0, stream>>>(ei, lofs, base2, edge_attr,
                                                    ai, aj, att, staged, es2);
    build_kernel<<<NBUCK, 256, 0, stream>>>(staged, btot, bbase, csr, rowStart);
    out_kernel<<<N_NODES / 8, 320, 0, stream>>>(h2, es2, csr, rowStart, out_buf, ssum);
    alpha_kernel<<<(N_EDGES * DIMS + B - 1) / B, B, 0, stream>>>(ei, es2, ssum, alpha_buf);
}

// Round 14
// 168.580 us; speedup vs baseline: 1.2660x; 1.0197x over previous
//
#include <hip/hip_runtime.h>
#include <hip/hip_bf16.h>
#include <math.h>

#define N_NODES 50000
#define N_EDGES 800000
#define DIMS 5
#define IN_C 32
#define OUT_C 32
#define FEAT 160            // DIMS*OUT_C
#define ATT_LD 65           // 2*OUT_C+1
#define NEG_SLOPE 0.2f
#define BSHIFT 7
#define BROWS 128                                   // rows per bucket
#define NBUCK ((N_NODES + BROWS - 1) / BROWS)       // 391
#define CAP 2560                                    // max edges/bucket (mean 2048, +11 sigma)
#define K1_EPB 4096
#define K1_BLOCKS ((N_EDGES + K1_EPB - 1) / K1_EPB) // 196

// ---- K1: per-block LDS histogram + per-edge local rank; fedge conversion ----
__global__ __launch_bounds__(1024) void hist_kernel(
        const int* __restrict__ ei, float* __restrict__ fedge,
        int* __restrict__ ghist, unsigned short* __restrict__ lofs) {
    __shared__ int hist[NBUCK];
    int blk = blockIdx.x, t = threadIdx.x;
    if (t < NBUCK) hist[t] = 0;
    __syncthreads();
#pragma unroll
    for (int u = 0; u < 4; ++u) {
        int e = blk * K1_EPB + u * 1024 + t;
        if (e < N_EDGES) {
            int r = ei[e];
            int c = ei[N_EDGES + e];
            __builtin_nontemporal_store((float)r, &fedge[e]);
            __builtin_nontemporal_store((float)c, &fedge[N_EDGES + e]);
            int b = r >> BSHIFT;
            int lo = atomicAdd(&hist[b], 1);
            lofs[e] = (unsigned short)lo;
        }
    }
    __syncthreads();
    if (t < NBUCK) ghist[blk * NBUCK + t] = hist[t];
}

// ---- K2a: column sums -> btot[b] ----
__global__ void colsum_kernel(const int* __restrict__ ghist, int* __restrict__ btot) {
    __shared__ int red[256];
    int b = blockIdx.x, t = threadIdx.x;
    int s = 0;
    for (int blk = t; blk < K1_BLOCKS; blk += 256) s += ghist[blk * NBUCK + b];
    red[t] = s;
    __syncthreads();
    for (int off = 128; off > 0; off >>= 1) {
        if (t < off) red[t] += red[t + off];
        __syncthreads();
    }
    if (t == 0) btot[b] = red[0];
}

// ---- K2b: exclusive scan of btot -> bbase ----
__global__ void bscan2_kernel(const int* __restrict__ btot, int* __restrict__ bbase) {
    __shared__ int buf[512];
    int t = threadIdx.x;
    int v = (t < NBUCK) ? btot[t] : 0;
    buf[t] = v;
    __syncthreads();
    for (int off = 1; off < 512; off <<= 1) {
        int add = (t >= off) ? buf[t - off] : 0;
        __syncthreads();
        buf[t] += add;
        __syncthreads();
    }
    if (t < NBUCK) bbase[t] = buf[t] - v;
}

// ---- K2c: per-bucket exclusive scan over blocks -> base2[blk][b] ----
__global__ void colscan_kernel(const int* __restrict__ ghist, const int* __restrict__ bbase,
                               int* __restrict__ base2) {
    __shared__ int buf[256];
    int b = blockIdx.x, t = threadIdx.x;
    int v = (t < K1_BLOCKS) ? ghist[t * NBUCK + b] : 0;
    buf[t] = v;
    __syncthreads();
    for (int off = 1; off < 256; off <<= 1) {
        int add = (t >= off) ? buf[t - off] : 0;
        __syncthreads();
        buf[t] += add;
        __syncthreads();
    }
    if (t < K1_BLOCKS) base2[t * NBUCK + b] = bbase[b] + buf[t] - v;
}

// ---- K3: place edges into bucket-sorted staged[] (8B) + fused es (bf16, edge order) ----
__global__ __launch_bounds__(1024) void place_es_kernel(
        const int* __restrict__ ei, const unsigned short* __restrict__ lofs,
        const int* __restrict__ base2,
        const float* __restrict__ edge_attr,
        const float* __restrict__ ai, const float* __restrict__ aj,
        const float* __restrict__ att,
        int2* __restrict__ staged, unsigned short* __restrict__ es2) {
    __shared__ int lbase[NBUCK];
    __shared__ float satte[DIMS];
    int blk = blockIdx.x, t = threadIdx.x;
    if (t < NBUCK) lbase[t] = base2[blk * NBUCK + t];
    if (t < DIMS) satte[t] = att[t * ATT_LD + 2 * OUT_C];
    __syncthreads();
#pragma unroll
    for (int u = 0; u < 4; ++u) {
        int e = blk * K1_EPB + u * 1024 + t;
        if (e < N_EDGES) {
            int r = ei[e];
            int c = ei[N_EDGES + e];
            int b = r >> BSHIFT;
            staged[lbase[b] + (int)lofs[e]] = make_int2(c, (e << BSHIFT) | (r & (BROWS - 1)));
            const float* air = ai + r * DIMS;
            const float* ajr = aj + c * DIMS;
            const float* ea  = edge_attr + (size_t)e * DIMS;
#pragma unroll
            for (int d = 0; d < DIMS; ++d) {
                float s = air[d] + ajr[d] + ea[d] * satte[d];
                s = (s > 0.f) ? s : NEG_SLOPE * s;
                __hip_bfloat16 h = __float2bfloat16(__expf(s));
                es2[(size_t)e * DIMS + d] = *(unsigned short*)&h;
            }
        }
    }
}

// ---- build: per-bucket CSR in LDS -> rowStart + csr ----
__global__ __launch_bounds__(256) void build_kernel(
        const int2* __restrict__ staged, const int* __restrict__ btot,
        const int* __restrict__ bbase,
        int2* __restrict__ csr, int* __restrict__ rowStart) {
    __shared__ int2 sst[CAP];
    __shared__ int rcount[BROWS];
    __shared__ int rexcl[BROWS];
    __shared__ int sbuf[BROWS];
    int b = blockIdx.x;
    int t = threadIdx.x;
    int cnt  = btot[b];
    int base = bbase[b];
    const int2* sg = staged + base;
    for (int i = t; i < cnt; i += 256) sst[i] = sg[i];
    if (t < BROWS) rcount[t] = 0;
    __syncthreads();
    for (int i = t; i < cnt; i += 256) atomicAdd(&rcount[sst[i].y & (BROWS - 1)], 1);
    __syncthreads();
    if (t < BROWS) sbuf[t] = rcount[t];
    __syncthreads();
    for (int off = 1; off < BROWS; off <<= 1) {
        int add = (t < BROWS && t >= off) ? sbuf[t - off] : 0;
        __syncthreads();
        if (t < BROWS) sbuf[t] += add;
        __syncthreads();
    }
    if (t < BROWS) {
        rexcl[t] = sbuf[t] - rcount[t];
        int idx = b * BROWS + t;
        if (idx <= N_NODES) rowStart[idx] = base + rexcl[t];
        rcount[t] = 0;                 // reuse as per-row cursor
    }
    __syncthreads();
    for (int i = t; i < cnt; i += 256) {
        int2 p = sst[i];
        int rl = p.y & (BROWS - 1);
        int lp = atomicAdd(&rcount[rl], 1);
        csr[base + rexcl[rl] + lp] = make_int2(p.x, p.y >> BSHIFT);
    }
}

// ---- fused h (bf16) + ai/aj. thread = (n, og) ----
__global__ __launch_bounds__(256) void hfused_kernel(
        const float* __restrict__ x, const float* __restrict__ W,
        const float* __restrict__ att,
        __hip_bfloat16* __restrict__ h2,
        float* __restrict__ ai, float* __restrict__ aj) {
    int idx = blockIdx.x * 256 + threadIdx.x;
    if (idx >= N_NODES * 8) return;
    int n = idx >> 3;
    int og = idx & 7;
    const float4* xr4 = (const float4*)(x + (size_t)n * FEAT);

    float acc[DIMS][4];
#pragma unroll
    for (int d = 0; d < DIMS; ++d)
#pragma unroll
        for (int q = 0; q < 4; ++q) acc[d][q] = 0.f;

#pragma unroll
    for (int ib = 0; ib < 8; ++ib) {
        float xs[20];
#pragma unroll
        for (int q = 0; q < 5; ++q) {
            float4 v = xr4[ib * 5 + q];
            xs[q * 4 + 0] = v.x; xs[q * 4 + 1] = v.y;
            xs[q * 4 + 2] = v.z; xs[q * 4 + 3] = v.w;
        }
#pragma unroll
        for (int ii = 0; ii < 4; ++ii) {
            int i = ib * 4 + ii;
#pragma unroll
            for (int d = 0; d < DIMS; ++d) {
                float xv = xs[ii * 5 + d];
                float4 wv = *(const float4*)(W + ((d * IN_C + i) * OUT_C) + og * 4);
                acc[d][0] += xv * wv.x; acc[d][1] += xv * wv.y;
                acc[d][2] += xv * wv.z; acc[d][3] += xv * wv.w;
            }
        }
    }

    __hip_bfloat16* hp = h2 + (size_t)n * FEAT + og * 4;
#pragma unroll
    for (int d = 0; d < DIMS; ++d) {
        union { __hip_bfloat16 h[4]; uint2 u; } pk;
        pk.h[0] = __float2bfloat16(acc[d][0]);
        pk.h[1] = __float2bfloat16(acc[d][1]);
        pk.h[2] = __float2bfloat16(acc[d][2]);
        pk.h[3] = __float2bfloat16(acc[d][3]);
        *(uint2*)(hp + d * OUT_C) = pk.u;
    }

    float pa[DIMS], pb[DIMS];
#pragma unroll
    for (int d = 0; d < DIMS; ++d) {
        const float* at = att + d * ATT_LD + og * 4;
        const float* bt = at + OUT_C;
        pa[d] = acc[d][0] * at[0] + acc[d][1] * at[1] + acc[d][2] * at[2] + acc[d][3] * at[3];
        pb[d] = acc[d][0] * bt[0] + acc[d][1] * bt[1] + acc[d][2] * bt[2] + acc[d][3] * bt[3];
    }
#pragma unroll
    for (int m = 1; m < 8; m <<= 1) {
#pragma unroll
        for (int d = 0; d < DIMS; ++d) {
            pa[d] += __shfl_xor(pa[d], m, 8);
            pb[d] += __shfl_xor(pb[d], m, 8);
        }
    }
    if (og == 0) {
#pragma unroll
        for (int d = 0; d < DIMS; ++d) {
            ai[n * DIMS + d] = pa[d];
            aj[n * DIMS + d] = pb[d];
        }
    }
}

__device__ inline float bf2f(unsigned short u) {
    return __uint_as_float(((unsigned)u) << 16);
}

// ---- out: 320-thr blocks, 8 nodes/block, 40 lanes/node; csr prefetch +
//      MASKED FINAL BATCH (no serial remainder round trips) ----
__global__ __launch_bounds__(320) void out_kernel(
        const __hip_bfloat16* __restrict__ h2,
        const unsigned short* __restrict__ es2,
        const int2* __restrict__ csr,
        const int* __restrict__ rowStart,
        float* __restrict__ out, float* __restrict__ ssum) {
    int g = threadIdx.x / 40;          // node group 0..7
    int l = threadIdx.x - g * 40;      // 0..39
    int node = blockIdx.x * 8 + g;
    int d = l >> 3;                    // 8 lanes per d
    int start = rowStart[node];
    int end   = rowStart[node + 1];
    float a0 = 0.f, a1 = 0.f, a2 = 0.f, a3 = 0.f, ss = 0.f;
    if (end > start) {
        int last = end - 1;
        int k = start;
        int2 ceA[8];
#pragma unroll
        for (int u = 0; u < 8; ++u) {
            int kk = k + u;
            ceA[u] = csr[kk <= last ? kk : last];
        }
        while (true) {
            int kn = k + 8;
            bool more = (kn < end);
            float av[8]; uint2 hv[8]; int2 ceB[8];
            // gathers for current (possibly masked) batch — ceA resident
#pragma unroll
            for (int u = 0; u < 8; ++u) {
                float a = bf2f(es2[(size_t)ceA[u].y * DIMS + d]);
                av[u] = (k + u < end) ? a : 0.f;
            }
#pragma unroll
            for (int u = 0; u < 8; ++u)
                hv[u] = *(const uint2*)(h2 + (size_t)ceA[u].x * FEAT + l * 4);
            // prefetch next batch's csr while gathers are in flight
            if (more) {
#pragma unroll
                for (int u = 0; u < 8; ++u) {
                    int kk = kn + u;
                    ceB[u] = csr[kk <= last ? kk : last];
                }
            }
#pragma unroll
            for (int u = 0; u < 8; ++u) {
                float a = av[u];
                ss += a;
                a0 += a * __uint_as_float(hv[u].x << 16);
                a1 += a * __uint_as_float(hv[u].x & 0xffff0000u);
                a2 += a * __uint_as_float(hv[u].y << 16);
                a3 += a * __uint_as_float(hv[u].y & 0xffff0000u);
            }
            if (!more) break;
            k = kn;
#pragma unroll
            for (int u = 0; u < 8; ++u) ceA[u] = ceB[u];
        }
    }
    float inv = 1.f / (ss + 1e-16f);
    union { float f[4]; unsigned long long u[2]; } o;
    o.f[0] = a0 * inv; o.f[1] = a1 * inv; o.f[2] = a2 * inv; o.f[3] = a3 * inv;
    unsigned long long* op = (unsigned long long*)(out + (size_t)node * FEAT + l * 4);
    __builtin_nontemporal_store(o.u[0], op);
    __builtin_nontemporal_store(o.u[1], op + 1);
    if ((l & 7) == 0) ssum[node * DIMS + d] = ss;
}

// ---- alpha = bf16(es) / ssum[row] ----
__global__ void alpha_kernel(const int* __restrict__ ei,
                             const unsigned short* __restrict__ es2,
                             const float* __restrict__ ssum,
                             float* __restrict__ alpha_buf) {
    int idx = blockIdx.x * blockDim.x + threadIdx.x;
    if (idx >= N_EDGES * DIMS) return;
    int e = idx / DIMS;
    int d = idx - e * DIMS;
    int r = ei[e];
    float a = bf2f(es2[idx]) / (ssum[r * DIMS + d] + 1e-16f);
    __builtin_nontemporal_store(a, &alpha_buf[idx]);
}

extern "C" void kernel_launch(void* const* d_in, const int* in_sizes, int n_in,
                              void* d_out, int out_size, void* d_ws, size_t ws_size,
                              hipStream_t stream) {
    const float* x         = (const float*)d_in[0];
    const int*   ei        = (const int*)d_in[1];
    const float* edge_attr = (const float*)d_in[2];
    const float* W         = (const float*)d_in[3];
    const float* att       = (const float*)d_in[4];

    float* out_buf   = (float*)d_out;                       // 8,000,000 f32
    float* alpha_buf = out_buf + (size_t)N_NODES * FEAT;    // 4,000,000 f32 (scratch until alpha)
    float* fedge     = alpha_buf + (size_t)N_EDGES * DIMS;  // 1,600,000 f32

    // scratch inside the alpha output region (dead until alpha_kernel runs last):
    int2* staged = (int2*)alpha_buf;                        // 6,400,000 B
    unsigned short* lofs = (unsigned short*)((char*)alpha_buf + 6400000); // 1,600,000 B

    char* wsb = (char*)d_ws;
    __hip_bfloat16* h2 = (__hip_bfloat16*)wsb;              //  0 .. 16,000,000
    float* ai     = (float*)(wsb + 16000000);               // 1,000,000 B
    float* aj     = (float*)(wsb + 17000000);               // 1,000,000 B
    float* ssum   = (float*)(wsb + 18000000);               // 1,000,000 B
    int2* csr     = (int2*)(wsb + 19000000);                // 6,400,000 B
    int* ghist    = (int*)(wsb + 25400000);                 // 306,544 B
    int* base2    = (int*)(wsb + 25710000);                 // 306,544 B
    int* btot     = (int*)(wsb + 26020000);                 // 1,564 B
    int* bbase    = (int*)(wsb + 26022000);                 // 1,564 B
    int* rowStart = (int*)(wsb + 26024000);                 // 200,004 B
    unsigned short* es2 = (unsigned short*)(wsb + 26225000);// 8,000,000 B -> end ~34.2 MB

    const int B = 256;

    hist_kernel<<<K1_BLOCKS, 1024, 0, stream>>>(ei, fedge, ghist, lofs);
    hfused_kernel<<<(N_NODES * 8 + B - 1) / B, B, 0, stream>>>(x, W, att, h2, ai, aj);
    colsum_kernel<<<NBUCK, 256, 0, stream>>>(ghist, btot);
    bscan2_kernel<<<1, 512, 0, stream>>>(btot, bbase);
    colscan_kernel<<<NBUCK, 256, 0, stream>>>(ghist, bbase, base2);
    place_es_kernel<<<K1_BLOCKS, 1024, 0, stream>>>(ei, lofs, base2, edge_attr,
                                                    ai, aj, att, staged, es2);
    build_kernel<<<NBUCK, 256, 0, stream>>>(staged, btot, bbase, csr, rowStart);
    out_kernel<<<N_NODES / 8, 320, 0, stream>>>(h2, es2, csr, rowStart, out_buf, ssum);
    alpha_kernel<<<(N_EDGES * DIMS + B - 1) / B, B, 0, stream>>>(ei, es2, ssum, alpha_buf);
}